// Round 10
// baseline (147.475 us; speedup 1.0000x reference)
//
#include <hip/hip_runtime.h>

#define D 128

typedef float f32x4 __attribute__((ext_vector_type(4)));
typedef float f32x8 __attribute__((ext_vector_type(8)));
typedef short s16x8 __attribute__((ext_vector_type(8)));
typedef unsigned short u16x8 __attribute__((ext_vector_type(8)));

static __device__ __forceinline__ unsigned short f2bf(float f) {
    unsigned int u = __float_as_uint(f);
    unsigned int r = (u + 0x7FFFu + ((u >> 16) & 1u)) >> 16;  // RNE
    return (unsigned short)r;
}
static __device__ __forceinline__ float bf2f(unsigned int lo16) {
    return __uint_as_float(lo16 << 16);
}

// ===========================================================================
// PRIMARY tier: rank-based CSR build + fused aggregate/GEMM
// ===========================================================================

// hist whose atomicAdd return value IS the edge's within-node rank (stored),
// + feature->bf16 + W->Wt bf16, fused.
__global__ void k_prep_rank(const int* __restrict__ dst, int* __restrict__ cnt,
                            int* __restrict__ rank,
                            const float* __restrict__ feature,
                            unsigned short* __restrict__ fb, int E, int NF4,
                            const float* __restrict__ W,
                            unsigned short* __restrict__ wt) {
    int tid = blockIdx.x * blockDim.x + threadIdx.x;
    int stride = gridDim.x * blockDim.x;
    for (int base = tid * 4; base < E; base += stride * 4) {
        if (base + 4 <= E) {
            int4 d4 = *reinterpret_cast<const int4*>(dst + base);
            int4 r4;
            r4.x = atomicAdd(&cnt[d4.x], 1);
            r4.y = atomicAdd(&cnt[d4.y], 1);
            r4.z = atomicAdd(&cnt[d4.z], 1);
            r4.w = atomicAdd(&cnt[d4.w], 1);
            *reinterpret_cast<int4*>(rank + base) = r4;
        } else {
            for (int i = base; i < E; ++i) rank[i] = atomicAdd(&cnt[dst[i]], 1);
        }
    }
    const f32x4* f4 = reinterpret_cast<const f32x4*>(feature);
    ushort4* fb4 = reinterpret_cast<ushort4*>(fb);
    for (int i = tid; i < NF4; i += stride) {
        f32x4 v = f4[i];
        ushort4 o;
        o.x = f2bf(v[0]);
        o.y = f2bf(v[1]);
        o.z = f2bf(v[2]);
        o.w = f2bf(v[3]);
        fb4[i] = o;
    }
    for (int i = tid; i < D * D; i += stride) {
        int n = i >> 7, k = i & 127;
        wt[i] = f2bf(W[k * D + n]);
    }
}

// unordered per-node base allocation (wave-aggregated single counter)
__global__ void k_alloc(const int* __restrict__ cnt, int* __restrict__ offset,
                        int* __restrict__ gtot, int N) {
    int i = blockIdx.x * blockDim.x + threadIdx.x;
    int lane = threadIdx.x & 63;
    int c = (i < N) ? cnt[i] : 0;
    int s = c;
    #pragma unroll
    for (int o = 1; o < 64; o <<= 1) {
        int t = __shfl_up(s, o);
        if (lane >= o) s += t;
    }
    int wavesum = __shfl(s, 63);
    int base = 0;
    if (lane == 0) base = atomicAdd(gtot, wavesum);
    base = __shfl(base, 0);
    if (i < N) offset[i] = base + s - c;
}

// atomic-free fill: pure permutation scatter using precomputed ranks.
__global__ void k_fill_rank(const int* __restrict__ src,
                            const int* __restrict__ dst,
                            const int* __restrict__ rank,
                            const int* __restrict__ offset,
                            unsigned short* __restrict__ srcs, int E) {
    int t = blockIdx.x * blockDim.x + threadIdx.x;
    int base = t * 4;
    if (base >= E) return;
    if (base + 4 <= E) {
        int4 d4 = *reinterpret_cast<const int4*>(dst + base);
        int4 s4 = *reinterpret_cast<const int4*>(src + base);
        int4 r4 = *reinterpret_cast<const int4*>(rank + base);
        int o0 = offset[d4.x];
        int o1 = offset[d4.y];
        int o2 = offset[d4.z];
        int o3 = offset[d4.w];
        srcs[o0 + r4.x] = (unsigned short)s4.x;
        srcs[o1 + r4.y] = (unsigned short)s4.y;
        srcs[o2 + r4.z] = (unsigned short)s4.z;
        srcs[o3 + r4.w] = (unsigned short)s4.w;
    } else {
        for (int i = base; i < E; ++i)
            srcs[offset[dst[i]] + rank[i]] = (unsigned short)src[i];
    }
}

// Fused aggregate + GEMM. Block = 256 threads (4 waves) owns 64 output rows.
// Wave wv aggregates its 16 nodes directly into the swizzled LDS A-tile,
// then computes its 16x128 output sub-tile via MFMA against LDS-staged Wt.
// LDS: A 64x256B = 16KB at 0, Wt 32KB at 16384. 48KB total -> 3 blocks/CU.
__global__ __launch_bounds__(256) void k_agg_gemm(
    const unsigned short* __restrict__ fb,
    const unsigned short* __restrict__ srcs, const int* __restrict__ offset,
    const int* __restrict__ cnt, const unsigned short* __restrict__ Wt,
    const float* __restrict__ b, float* __restrict__ out, int N) {
    __shared__ char lds[49152];

    int t = threadIdx.x;
    int row0 = blockIdx.x * 64;
    int wv = t >> 6;
    int lane = t & 63;
    int sub = lane >> 4;   // 0..3
    int l15 = lane & 15;

    // stage Wt (swizzled): 2048 x 16B chunks / 256 threads = 8 each
    #pragma unroll
    for (int i = 0; i < 8; ++i) {
        int chunk = i * 256 + t;
        int row = chunk >> 4;
        int c16 = chunk & 15;
        int ldsoff = 16384 + row * 256 + ((c16 * 16) ^ ((row & 7) << 4));
        f32x4 v = *reinterpret_cast<const f32x4*>(Wt + (size_t)row * D + c16 * 8);
        *reinterpret_cast<f32x4*>(&lds[ldsoff]) = v;
    }

    // gather phase: wave wv handles local rows wv*16 .. wv*16+15
    for (int r = 0; r < 16; ++r) {
        int lr = wv * 16 + r;
        int node = row0 + lr;
        int ldsa = lr * 256 + ((l15 * 16) ^ ((lr & 7) << 4));
        if (node >= N) continue;
        int n = cnt[node];
        if (n == 0) {
            if (sub == 0) {
                u16x8 v = *reinterpret_cast<const u16x8*>(fb + (size_t)node * D + l15 * 8);
                *reinterpret_cast<u16x8*>(&lds[ldsa]) = v;
            }
            continue;
        }
        int base = offset[node];
        f32x8 acc = {0.f, 0.f, 0.f, 0.f, 0.f, 0.f, 0.f, 0.f};
        int j = 0;
        for (; j + 8 <= n; j += 8) {
            int s0 = srcs[base + j + sub];
            int s1 = srcs[base + j + 4 + sub];
            u16x8 v0 = *reinterpret_cast<const u16x8*>(fb + (size_t)s0 * D + l15 * 8);
            u16x8 v1 = *reinterpret_cast<const u16x8*>(fb + (size_t)s1 * D + l15 * 8);
            #pragma unroll
            for (int q = 0; q < 8; ++q) acc[q] += bf2f((unsigned int)(unsigned short)v0[q]);
            #pragma unroll
            for (int q = 0; q < 8; ++q) acc[q] += bf2f((unsigned int)(unsigned short)v1[q]);
        }
        for (; j < n; j += 4) {
            if (j + sub < n) {
                int s0 = srcs[base + j + sub];
                u16x8 v0 = *reinterpret_cast<const u16x8*>(fb + (size_t)s0 * D + l15 * 8);
                #pragma unroll
                for (int q = 0; q < 8; ++q) acc[q] += bf2f((unsigned int)(unsigned short)v0[q]);
            }
        }
        #pragma unroll
        for (int q = 0; q < 8; ++q) acc[q] += __shfl_xor(acc[q], 16);
        #pragma unroll
        for (int q = 0; q < 8; ++q) acc[q] += __shfl_xor(acc[q], 32);
        if (sub == 0) {
            float inv = 1.f / (float)n;
            u16x8 o;
            #pragma unroll
            for (int q = 0; q < 8; ++q) o[q] = f2bf(acc[q] * inv);
            *reinterpret_cast<u16x8*>(&lds[ldsa]) = o;
        }
    }
    __syncthreads();

    // MFMA phase: wave wv computes rows wv*16..+16 x 128 cols
    f32x4 acc[8];
    #pragma unroll
    for (int n = 0; n < 8; ++n) acc[n] = (f32x4){0.f, 0.f, 0.f, 0.f};

    #pragma unroll
    for (int kk = 0; kk < 4; ++kk) {
        int kb = kk * 64 + sub * 16;
        int ra = wv * 16 + l15;
        s16x8 af = *reinterpret_cast<const s16x8*>(
            &lds[ra * 256 + (kb ^ ((ra & 7) << 4))]);
        s16x8 bf[8];
        #pragma unroll
        for (int n = 0; n < 8; ++n) {
            int rb = n * 16 + l15;
            bf[n] = *reinterpret_cast<const s16x8*>(
                &lds[16384 + rb * 256 + (kb ^ ((rb & 7) << 4))]);
        }
        #pragma unroll
        for (int n = 0; n < 8; ++n)
            acc[n] = __builtin_amdgcn_mfma_f32_16x16x32_bf16(af, bf[n], acc[n],
                                                             0, 0, 0);
    }

    #pragma unroll
    for (int n = 0; n < 8; ++n) {
        int col = n * 16 + l15;
        float bv = b[col];
        int rbase = row0 + wv * 16 + sub * 4;
        #pragma unroll
        for (int j = 0; j < 4; ++j) {
            int row = rbase + j;
            if (row < N)
                out[(size_t)row * D + col] = fmaxf(acc[n][j] + bv, 0.f);
        }
    }
}

// ===========================================================================
// Fallback tier: float-atomic scatter + vector-ALU finalize
// ===========================================================================
__global__ void gcn_scatter(const float* __restrict__ feature,
                            const int* __restrict__ src,
                            const int* __restrict__ dst,
                            float* __restrict__ agg,
                            float* __restrict__ deg, int n_edges) {
    int gid = blockIdx.x * blockDim.x + threadIdx.x;
    int e = gid >> 6;
    int lane = gid & 63;
    if (e >= n_edges) return;
    int s = src[e];
    int d = dst[e];
    const float2 v =
        *reinterpret_cast<const float2*>(feature + (size_t)s * D + lane * 2);
    float* o = agg + (size_t)d * D + lane * 2;
    atomicAdd(o, v.x);
    atomicAdd(o + 1, v.y);
    if (lane == 0) atomicAdd(deg + d, 1.0f);
}

__global__ __launch_bounds__(256, 2) void gcn_finalize(
    float* __restrict__ inout, const float* __restrict__ feature,
    const float* __restrict__ W, const float* __restrict__ b,
    const float* __restrict__ deg, int n_nodes) {
    __shared__ float Ws[D * D];
    __shared__ float bs[D];
    __shared__ float hs[4][4][D];

    for (int i = threadIdx.x; i < (D * D) / 4; i += blockDim.x)
        reinterpret_cast<float4*>(Ws)[i] = reinterpret_cast<const float4*>(W)[i];
    if (threadIdx.x < D) bs[threadIdx.x] = b[threadIdx.x];
    __syncthreads();

    int wave = threadIdx.x >> 6;
    int lane = threadIdx.x & 63;
    int gwave = (blockIdx.x * blockDim.x + threadIdx.x) >> 6;
    int nwaves = (gridDim.x * blockDim.x) >> 6;
    int ngroups = (n_nodes + 3) / 4;

    for (int g = gwave; g < ngroups; g += nwaves) {
        int row0 = g * 4;
        #pragma unroll
        for (int r = 0; r < 4; ++r) {
            int row = row0 + r;
            if (row < n_nodes) {
                float2 h2;
                float dg = deg[row];
                if (dg > 0.f) {
                    float2 a = *reinterpret_cast<const float2*>(
                        inout + (size_t)row * D + lane * 2);
                    float rd = 1.f / dg;
                    h2.x = a.x * rd;
                    h2.y = a.y * rd;
                } else {
                    h2 = *reinterpret_cast<const float2*>(
                        feature + (size_t)row * D + lane * 2);
                }
                reinterpret_cast<float2*>(hs[wave][r])[lane] = h2;
            }
        }
        float acc2[4][2];
        #pragma unroll
        for (int r = 0; r < 4; ++r) {
            acc2[r][0] = bs[lane];
            acc2[r][1] = bs[lane + 64];
        }
        #pragma unroll 4
        for (int k = 0; k < D; ++k) {
            float w0 = Ws[k * D + lane];
            float w1 = Ws[k * D + lane + 64];
            #pragma unroll
            for (int r = 0; r < 4; ++r) {
                float hk = hs[wave][r][k];
                acc2[r][0] = fmaf(hk, w0, acc2[r][0]);
                acc2[r][1] = fmaf(hk, w1, acc2[r][1]);
            }
        }
        #pragma unroll
        for (int r = 0; r < 4; ++r) {
            int row = row0 + r;
            if (row < n_nodes) {
                inout[(size_t)row * D + lane] = fmaxf(acc2[r][0], 0.f);
                inout[(size_t)row * D + lane + 64] = fmaxf(acc2[r][1], 0.f);
            }
        }
    }
}

extern "C" void kernel_launch(void* const* d_in, const int* in_sizes, int n_in,
                              void* d_out, int out_size, void* d_ws,
                              size_t ws_size, hipStream_t stream) {
    const float* feature = (const float*)d_in[0];
    const float* W = (const float*)d_in[1];
    const float* b = (const float*)d_in[2];
    const int* src = (const int*)d_in[3];
    const int* dst = (const int*)d_in[4];
    int n_edges = in_sizes[3];
    int n_nodes = in_sizes[0] / D;

    float* out = (float*)d_out;
    int block = 256;

    // ---- PRIMARY layout (ints): cnt[N] | gtot[1] | offset[N] | rank[E]
    //      then u16: srcs[E] | fb[N*D] | wt[D*D]
    size_t intsA = (size_t)2 * n_nodes + 1 + n_edges;
    size_t a_srcs_off = (intsA * sizeof(int) + 255) & ~(size_t)255;
    size_t a_fb_off = (a_srcs_off + (size_t)n_edges * 2 + 255) & ~(size_t)255;
    size_t a_wt_off = (a_fb_off + (size_t)n_nodes * D * 2 + 255) & ~(size_t)255;
    size_t need_a = a_wt_off + (size_t)D * D * 2;

    if (n_nodes < 65536 && ws_size >= need_a) {
        int* cnt = (int*)d_ws;
        int* gtot = cnt + n_nodes;
        int* offset = gtot + 1;
        int* rank = offset + n_nodes;
        unsigned short* srcs = (unsigned short*)((char*)d_ws + a_srcs_off);
        unsigned short* fb = (unsigned short*)((char*)d_ws + a_fb_off);
        unsigned short* wt = (unsigned short*)((char*)d_ws + a_wt_off);

        hipMemsetAsync(cnt, 0, (size_t)(n_nodes + 1) * sizeof(int), stream);
        k_prep_rank<<<2048, block, 0, stream>>>(dst, cnt, rank, feature, fb,
                                                n_edges, n_nodes * D / 4, W, wt);
        k_alloc<<<(n_nodes + block - 1) / block, block, 0, stream>>>(
            cnt, offset, gtot, n_nodes);
        k_fill_rank<<<(n_edges / 4 + block) / block, block, 0, stream>>>(
            src, dst, rank, offset, srcs, n_edges);
        k_agg_gemm<<<(n_nodes + 63) / 64, block, 0, stream>>>(
            fb, srcs, offset, cnt, wt, b, out, n_nodes);
    } else {
        float* deg = (float*)d_ws;
        hipMemsetAsync(out, 0, (size_t)out_size * sizeof(float), stream);
        hipMemsetAsync(deg, 0, (size_t)n_nodes * sizeof(float), stream);
        long long total_threads = (long long)n_edges * 64;
        int grid = (int)((total_threads + block - 1) / block);
        gcn_scatter<<<grid, block, 0, stream>>>(feature, src, dst, out, deg,
                                                n_edges);
        gcn_finalize<<<512, block, 0, stream>>>(out, feature, W, b, deg,
                                                n_nodes);
    }
}

// Round 13
// 105.273 us; speedup vs baseline: 1.4009x; 1.4009x over previous
//
#include <hip/hip_runtime.h>

#define D 128

typedef float f32x4 __attribute__((ext_vector_type(4)));
typedef float f32x8 __attribute__((ext_vector_type(8)));
typedef short s16x8 __attribute__((ext_vector_type(8)));
typedef unsigned short u16x8 __attribute__((ext_vector_type(8)));

static __device__ __forceinline__ unsigned short f2bf(float f) {
    unsigned int u = __float_as_uint(f);
    unsigned int r = (u + 0x7FFFu + ((u >> 16) & 1u)) >> 16;  // RNE
    return (unsigned short)r;
}
static __device__ __forceinline__ float bf2f(unsigned int lo16) {
    return __uint_as_float(lo16 << 16);
}

// ===========================================================================
// PRIMARY tier: rank-based CSR build + split aggregate / MFMA GEMM
// (exact round-9 configuration; rank buffer 16B-aligned)
// ===========================================================================

// hist whose atomicAdd return value IS the edge's within-node rank (stored),
// + feature->bf16 + W->Wt bf16, fused.
__global__ void k_prep_rank(const int* __restrict__ dst, int* __restrict__ cnt,
                            int* __restrict__ rank,
                            const float* __restrict__ feature,
                            unsigned short* __restrict__ fb, int E, int NF4,
                            const float* __restrict__ W,
                            unsigned short* __restrict__ wt) {
    int tid = blockIdx.x * blockDim.x + threadIdx.x;
    int stride = gridDim.x * blockDim.x;
    for (int base = tid * 4; base < E; base += stride * 4) {
        if (base + 4 <= E) {
            int4 d4 = *reinterpret_cast<const int4*>(dst + base);
            int4 r4;
            r4.x = atomicAdd(&cnt[d4.x], 1);
            r4.y = atomicAdd(&cnt[d4.y], 1);
            r4.z = atomicAdd(&cnt[d4.z], 1);
            r4.w = atomicAdd(&cnt[d4.w], 1);
            *reinterpret_cast<int4*>(rank + base) = r4;
        } else {
            for (int i = base; i < E; ++i) rank[i] = atomicAdd(&cnt[dst[i]], 1);
        }
    }
    const f32x4* f4 = reinterpret_cast<const f32x4*>(feature);
    ushort4* fb4 = reinterpret_cast<ushort4*>(fb);
    for (int i = tid; i < NF4; i += stride) {
        f32x4 v = f4[i];
        ushort4 o;
        o.x = f2bf(v[0]);
        o.y = f2bf(v[1]);
        o.z = f2bf(v[2]);
        o.w = f2bf(v[3]);
        fb4[i] = o;
    }
    for (int i = tid; i < D * D; i += stride) {
        int n = i >> 7, k = i & 127;
        wt[i] = f2bf(W[k * D + n]);
    }
}

// unordered per-node base allocation (wave-aggregated single counter)
__global__ void k_alloc(const int* __restrict__ cnt, int* __restrict__ offset,
                        int* __restrict__ gtot, int N) {
    int i = blockIdx.x * blockDim.x + threadIdx.x;
    int lane = threadIdx.x & 63;
    int c = (i < N) ? cnt[i] : 0;
    int s = c;
    #pragma unroll
    for (int o = 1; o < 64; o <<= 1) {
        int t = __shfl_up(s, o);
        if (lane >= o) s += t;
    }
    int wavesum = __shfl(s, 63);
    int base = 0;
    if (lane == 0) base = atomicAdd(gtot, wavesum);
    base = __shfl(base, 0);
    if (i < N) offset[i] = base + s - c;
}

// atomic-free fill: pure permutation scatter using precomputed ranks.
__global__ void k_fill_rank(const int* __restrict__ src,
                            const int* __restrict__ dst,
                            const int* __restrict__ rank,
                            const int* __restrict__ offset,
                            unsigned short* __restrict__ srcs, int E) {
    int t = blockIdx.x * blockDim.x + threadIdx.x;
    int base = t * 4;
    if (base >= E) return;
    if (base + 4 <= E) {
        int4 d4 = *reinterpret_cast<const int4*>(dst + base);
        int4 s4 = *reinterpret_cast<const int4*>(src + base);
        int4 r4 = *reinterpret_cast<const int4*>(rank + base);
        int o0 = offset[d4.x];
        int o1 = offset[d4.y];
        int o2 = offset[d4.z];
        int o3 = offset[d4.w];
        srcs[o0 + r4.x] = (unsigned short)s4.x;
        srcs[o1 + r4.y] = (unsigned short)s4.y;
        srcs[o2 + r4.z] = (unsigned short)s4.z;
        srcs[o3 + r4.w] = (unsigned short)s4.w;
    } else {
        for (int i = base; i < E; ++i)
            srcs[offset[dst[i]] + rank[i]] = (unsigned short)src[i];
    }
}

// aggregate from bf16 feature: one wave per node, 4 edges in flight
__global__ __launch_bounds__(256) void k_aggregate_u16(
    const unsigned short* __restrict__ fb,
    const unsigned short* __restrict__ srcs, const int* __restrict__ offset,
    const int* __restrict__ cnt, unsigned short* __restrict__ hb, int N) {
    int w = (blockIdx.x * blockDim.x + threadIdx.x) >> 6;
    int lane = threadIdx.x & 63;
    if (w >= N) return;
    int sub = lane >> 4;
    int l15 = lane & 15;
    int n = cnt[w];
    if (n == 0) {
        if (sub == 0) {
            u16x8 v = *reinterpret_cast<const u16x8*>(fb + (size_t)w * D + l15 * 8);
            *reinterpret_cast<u16x8*>(hb + (size_t)w * D + l15 * 8) = v;
        }
        return;
    }
    int base = offset[w];
    f32x8 acc = {0.f, 0.f, 0.f, 0.f, 0.f, 0.f, 0.f, 0.f};
    int j = 0;
    for (; j + 8 <= n; j += 8) {
        int s0 = srcs[base + j + sub];
        int s1 = srcs[base + j + 4 + sub];
        u16x8 v0 = *reinterpret_cast<const u16x8*>(fb + (size_t)s0 * D + l15 * 8);
        u16x8 v1 = *reinterpret_cast<const u16x8*>(fb + (size_t)s1 * D + l15 * 8);
        #pragma unroll
        for (int q = 0; q < 8; ++q) acc[q] += bf2f((unsigned int)(unsigned short)v0[q]);
        #pragma unroll
        for (int q = 0; q < 8; ++q) acc[q] += bf2f((unsigned int)(unsigned short)v1[q]);
    }
    for (; j < n; j += 4) {
        if (j + sub < n) {
            int s0 = srcs[base + j + sub];
            u16x8 v0 = *reinterpret_cast<const u16x8*>(fb + (size_t)s0 * D + l15 * 8);
            #pragma unroll
            for (int q = 0; q < 8; ++q) acc[q] += bf2f((unsigned int)(unsigned short)v0[q]);
        }
    }
    #pragma unroll
    for (int q = 0; q < 8; ++q) acc[q] += __shfl_xor(acc[q], 16);
    #pragma unroll
    for (int q = 0; q < 8; ++q) acc[q] += __shfl_xor(acc[q], 32);
    if (sub == 0) {
        float r = 1.f / (float)n;
        u16x8 o;
        #pragma unroll
        for (int q = 0; q < 8; ++q) o[q] = f2bf(acc[q] * r);
        *reinterpret_cast<u16x8*>(hb + (size_t)w * D + l15 * 8) = o;
    }
}

// ===========================================================================
// Finalize GEMM: out = relu(h @ W + b). XOR-swizzled LDS, 16x16x32 MFMA.
// ===========================================================================
__global__ __launch_bounds__(256) void k_finalize_mfma(
    const unsigned short* __restrict__ hb, const unsigned short* __restrict__ Wt,
    const float* __restrict__ b, float* __restrict__ out, int N) {
    __shared__ char lds[65536];

    int t = threadIdx.x;
    int row0 = blockIdx.x * 128;

    #pragma unroll
    for (int i = 0; i < 8; ++i) {
        int chunk = i * 256 + t;
        int row = chunk >> 4;
        int c16 = chunk & 15;
        int ldsoff = row * 256 + ((c16 * 16) ^ ((row & 7) << 4));
        f32x4 v = {0.f, 0.f, 0.f, 0.f};
        int grow = row0 + row;
        if (grow < N)
            v = *reinterpret_cast<const f32x4*>(hb + (size_t)grow * D + c16 * 8);
        *reinterpret_cast<f32x4*>(&lds[ldsoff]) = v;
    }
    #pragma unroll
    for (int i = 0; i < 8; ++i) {
        int chunk = i * 256 + t;
        int row = chunk >> 4;
        int c16 = chunk & 15;
        int ldsoff = 32768 + row * 256 + ((c16 * 16) ^ ((row & 7) << 4));
        f32x4 v = *reinterpret_cast<const f32x4*>(Wt + (size_t)row * D + c16 * 8);
        *reinterpret_cast<f32x4*>(&lds[ldsoff]) = v;
    }
    __syncthreads();

    int wv = t >> 6;
    int l = t & 63;
    int l15 = l & 15;
    int lhi = l >> 4;

    f32x4 acc[2][8];
    #pragma unroll
    for (int m = 0; m < 2; ++m)
        #pragma unroll
        for (int n = 0; n < 8; ++n) acc[m][n] = (f32x4){0.f, 0.f, 0.f, 0.f};

    #pragma unroll
    for (int kk = 0; kk < 4; ++kk) {
        int kb = kk * 64 + lhi * 16;
        s16x8 af[2], bf[8];
        #pragma unroll
        for (int m = 0; m < 2; ++m) {
            int r = wv * 32 + m * 16 + l15;
            af[m] = *reinterpret_cast<const s16x8*>(
                &lds[r * 256 + (kb ^ ((r & 7) << 4))]);
        }
        #pragma unroll
        for (int n = 0; n < 8; ++n) {
            int r = n * 16 + l15;
            bf[n] = *reinterpret_cast<const s16x8*>(
                &lds[32768 + r * 256 + (kb ^ ((r & 7) << 4))]);
        }
        #pragma unroll
        for (int m = 0; m < 2; ++m)
            #pragma unroll
            for (int n = 0; n < 8; ++n)
                acc[m][n] = __builtin_amdgcn_mfma_f32_16x16x32_bf16(
                    af[m], bf[n], acc[m][n], 0, 0, 0);
    }

    #pragma unroll
    for (int n = 0; n < 8; ++n) {
        int col = n * 16 + l15;
        float bv = b[col];
        #pragma unroll
        for (int m = 0; m < 2; ++m) {
            int rbase = row0 + wv * 32 + m * 16 + lhi * 4;
            #pragma unroll
            for (int j = 0; j < 4; ++j) {
                int row = rbase + j;
                if (row < N)
                    out[(size_t)row * D + col] = fmaxf(acc[m][n][j] + bv, 0.f);
            }
        }
    }
}

// ===========================================================================
// Fallback tier: float-atomic scatter + vector-ALU finalize
// ===========================================================================
__global__ void gcn_scatter(const float* __restrict__ feature,
                            const int* __restrict__ src,
                            const int* __restrict__ dst,
                            float* __restrict__ agg,
                            float* __restrict__ deg, int n_edges) {
    int gid = blockIdx.x * blockDim.x + threadIdx.x;
    int e = gid >> 6;
    int lane = gid & 63;
    if (e >= n_edges) return;
    int s = src[e];
    int d = dst[e];
    const float2 v =
        *reinterpret_cast<const float2*>(feature + (size_t)s * D + lane * 2);
    float* o = agg + (size_t)d * D + lane * 2;
    atomicAdd(o, v.x);
    atomicAdd(o + 1, v.y);
    if (lane == 0) atomicAdd(deg + d, 1.0f);
}

__global__ __launch_bounds__(256, 2) void gcn_finalize(
    float* __restrict__ inout, const float* __restrict__ feature,
    const float* __restrict__ W, const float* __restrict__ b,
    const float* __restrict__ deg, int n_nodes) {
    __shared__ float Ws[D * D];
    __shared__ float bs[D];
    __shared__ float hs[4][4][D];

    for (int i = threadIdx.x; i < (D * D) / 4; i += blockDim.x)
        reinterpret_cast<float4*>(Ws)[i] = reinterpret_cast<const float4*>(W)[i];
    if (threadIdx.x < D) bs[threadIdx.x] = b[threadIdx.x];
    __syncthreads();

    int wave = threadIdx.x >> 6;
    int lane = threadIdx.x & 63;
    int gwave = (blockIdx.x * blockDim.x + threadIdx.x) >> 6;
    int nwaves = (gridDim.x * blockDim.x) >> 6;
    int ngroups = (n_nodes + 3) / 4;

    for (int g = gwave; g < ngroups; g += nwaves) {
        int row0 = g * 4;
        #pragma unroll
        for (int r = 0; r < 4; ++r) {
            int row = row0 + r;
            if (row < n_nodes) {
                float2 h2;
                float dg = deg[row];
                if (dg > 0.f) {
                    float2 a = *reinterpret_cast<const float2*>(
                        inout + (size_t)row * D + lane * 2);
                    float rd = 1.f / dg;
                    h2.x = a.x * rd;
                    h2.y = a.y * rd;
                } else {
                    h2 = *reinterpret_cast<const float2*>(
                        feature + (size_t)row * D + lane * 2);
                }
                reinterpret_cast<float2*>(hs[wave][r])[lane] = h2;
            }
        }
        float acc2[4][2];
        #pragma unroll
        for (int r = 0; r < 4; ++r) {
            acc2[r][0] = bs[lane];
            acc2[r][1] = bs[lane + 64];
        }
        #pragma unroll 4
        for (int k = 0; k < D; ++k) {
            float w0 = Ws[k * D + lane];
            float w1 = Ws[k * D + lane + 64];
            #pragma unroll
            for (int r = 0; r < 4; ++r) {
                float hk = hs[wave][r][k];
                acc2[r][0] = fmaf(hk, w0, acc2[r][0]);
                acc2[r][1] = fmaf(hk, w1, acc2[r][1]);
            }
        }
        #pragma unroll
        for (int r = 0; r < 4; ++r) {
            int row = row0 + r;
            if (row < n_nodes) {
                inout[(size_t)row * D + lane] = fmaxf(acc2[r][0], 0.f);
                inout[(size_t)row * D + lane + 64] = fmaxf(acc2[r][1], 0.f);
            }
        }
    }
}

extern "C" void kernel_launch(void* const* d_in, const int* in_sizes, int n_in,
                              void* d_out, int out_size, void* d_ws,
                              size_t ws_size, hipStream_t stream) {
    const float* feature = (const float*)d_in[0];
    const float* W = (const float*)d_in[1];
    const float* b = (const float*)d_in[2];
    const int* src = (const int*)d_in[3];
    const int* dst = (const int*)d_in[4];
    int n_edges = in_sizes[3];
    int n_nodes = in_sizes[0] / D;

    float* out = (float*)d_out;
    int block = 256;
    int nrows_pad = ((n_nodes + 127) / 128) * 128;

    // ---- PRIMARY layout (ints): cnt[N] | gtot[1] | offset[N] | pad[to 16B] |
    //      rank[E]  then u16: srcs[E] | fb[N*D] | hb[pad*D] | wt[D*D]
    size_t rank_idx = (((size_t)2 * n_nodes + 1) + 3) & ~(size_t)3;  // 16B align
    size_t intsA = rank_idx + n_edges;
    size_t a_srcs_off = (intsA * sizeof(int) + 255) & ~(size_t)255;
    size_t a_fb_off = (a_srcs_off + (size_t)n_edges * 2 + 255) & ~(size_t)255;
    size_t a_hb_off = (a_fb_off + (size_t)n_nodes * D * 2 + 255) & ~(size_t)255;
    size_t a_wt_off = a_hb_off + (size_t)nrows_pad * D * 2;
    size_t need_a = a_wt_off + (size_t)D * D * 2;

    if (n_nodes < 65536 && ws_size >= need_a) {
        int* cnt = (int*)d_ws;
        int* gtot = cnt + n_nodes;
        int* offset = gtot + 1;
        int* rank = (int*)d_ws + rank_idx;
        unsigned short* srcs = (unsigned short*)((char*)d_ws + a_srcs_off);
        unsigned short* fb = (unsigned short*)((char*)d_ws + a_fb_off);
        unsigned short* hb = (unsigned short*)((char*)d_ws + a_hb_off);
        unsigned short* wt = (unsigned short*)((char*)d_ws + a_wt_off);

        hipMemsetAsync(cnt, 0, (size_t)(n_nodes + 1) * sizeof(int), stream);
        k_prep_rank<<<2048, block, 0, stream>>>(dst, cnt, rank, feature, fb,
                                                n_edges, n_nodes * D / 4, W, wt);
        k_alloc<<<(n_nodes + block - 1) / block, block, 0, stream>>>(
            cnt, offset, gtot, n_nodes);
        k_fill_rank<<<(n_edges / 4 + block) / block, block, 0, stream>>>(
            src, dst, rank, offset, srcs, n_edges);
        k_aggregate_u16<<<((size_t)n_nodes * 64 + block - 1) / block, block, 0,
                          stream>>>(fb, srcs, offset, cnt, hb, n_nodes);
        k_finalize_mfma<<<(n_nodes + 127) / 128, block, 0, stream>>>(
            hb, wt, b, out, n_nodes);
    } else {
        float* deg = (float*)d_ws;
        hipMemsetAsync(out, 0, (size_t)out_size * sizeof(float), stream);
        hipMemsetAsync(deg, 0, (size_t)n_nodes * sizeof(float), stream);
        long long total_threads = (long long)n_edges * 64;
        int grid = (int)((total_threads + block - 1) / block);
        gcn_scatter<<<grid, block, 0, stream>>>(feature, src, dst, out, deg,
                                                n_edges);
        gcn_finalize<<<512, block, 0, stream>>>(out, feature, W, b, deg,
                                                n_nodes);
    }
}